// Round 1
// baseline (1214.327 us; speedup 1.0000x reference)
//
#include <hip/hip_runtime.h>
#include <math.h>

#define NODES   100000
#define EDGES   1200000
#define GRAPHS  512
#define DIM     64
#define NT      10
#define KTOT    576   // 64 base + 64*8 spline features

// ---------------------------------------------------------------------------
// Uniform cubic B-spline bases matching the reference Cox-de Boor recursion.
// grid g[j] = (j-3)*0.4 - 1, j=0..11. Order-3 bases b[0..7]; at most 4 nonzero.
// tt = (x+2.2)/0.4 ; interval m = floor(tt) valid in [0,10]; nonzero j = m-3..m
// clipped to [0,7]. Out-of-range x -> all zero (matches half-open indicators).
// ---------------------------------------------------------------------------
__device__ __forceinline__ void spline_bases(float x, float* b) {
    float tt  = fmaf(x, 2.5f, 5.5f);
    float fm  = floorf(tt);
    int   m   = (int)fm;
    float u   = tt - fm;
    float um1 = 1.f - u;
    float v3  = u * u * u * (1.f / 6.f);
    float v0  = um1 * um1 * um1 * (1.f / 6.f);
    float B2m1 = 0.5f * ((u + 1.f) * um1 + (2.f - u) * u);
    float v1  = ((u + 2.f) * um1 * um1 * 0.5f + (2.f - u) * B2m1) * (1.f / 3.f);
    float v2  = ((u + 1.f) * B2m1 + (3.f - u) * u * u * 0.5f) * (1.f / 3.f);
    bool inr  = (m >= 0) && (m <= 10);
#pragma unroll
    for (int j = 0; j < 8; ++j) {
        float bv = 0.f;
        bv = (j == m - 3) ? v0 : bv;
        bv = (j == m - 2) ? v1 : bv;
        bv = (j == m - 1) ? v2 : bv;
        bv = (j == m)     ? v3 : bv;
        b[j] = inr ? bv : 0.f;
    }
}

__device__ __forceinline__ float silu(float x) {
    return x / (1.f + __expf(-x));
}

// ---------------------------------------------------------------------------
// Combine base_w (transposed) and spline_w*scaler into Wc[k][o], k=0..575.
//   k < 64        : Wc[k][o] = base_w[o][k]
//   k = 64+i*8+g  : Wc[k][o] = spline_w[o][i][g] * scaler[o][i]
// ---------------------------------------------------------------------------
__global__ void prep_w(const float* __restrict__ bw, const float* __restrict__ sw,
                       const float* __restrict__ sc, float* __restrict__ Wc) {
    int idx = blockIdx.x * 256 + threadIdx.x;
    if (idx >= KTOT * DIM) return;
    int k = idx >> 6, o = idx & 63;
    float v;
    if (k < DIM) {
        v = bw[o * DIM + k];
    } else {
        int i = (k - DIM) >> 3, g = (k - DIM) & 7;
        v = sw[(o * DIM + i) * 8 + g] * sc[o * DIM + i];
    }
    Wc[idx] = v;
}

// ---------------------------------------------------------------------------
// agg[dst] += x[src] over all edges. One thread per (edge, feature).
// e is wave-uniform (tid>>6) -> index loads become scalar loads.
// ---------------------------------------------------------------------------
__global__ void scatter_add(const float* __restrict__ x, const int* __restrict__ ei,
                            float* __restrict__ agg) {
    int tid = blockIdx.x * 256 + threadIdx.x;
    int e = tid >> 6;
    int f = tid & 63;
    if (e >= EDGES) return;
    int src = ei[e];
    int dst = ei[EDGES + e];
    atomicAdd(&agg[dst * DIM + f], x[src * DIM + f]);
}

// ---------------------------------------------------------------------------
// h[n] = KAN(x[n] + agg[n]).  One thread per node, acc[64] in VGPRs,
// weights via wave-uniform (scalar) loads, features staged in padded LDS.
// Safe to run in place (out == xin): a block only reads its own 128 rows
// and writes them after the barrier.
// ---------------------------------------------------------------------------
__global__ __launch_bounds__(128) void kan_layer(const float* xin,
                                                 const float* __restrict__ agg,
                                                 const float* __restrict__ Wc,
                                                 float* out) {
    __shared__ float v[128][65];
    const int t = threadIdx.x;
    const int base = blockIdx.x * 128 * DIM;

    // coalesced load of this block's 128 node rows (x + agg)
#pragma unroll 4
    for (int j = 0; j < 64; ++j) {
        int idx = base + t + j * 128;
        if (idx < NODES * DIM) {
            int off = t + j * 128;
            v[off >> 6][off & 63] = xin[idx] + agg[idx];
        }
    }
    __syncthreads();

    const int n = blockIdx.x * 128 + t;
    const bool active = (n < NODES);
    float acc[DIM];
#pragma unroll
    for (int o = 0; o < DIM; ++o) acc[o] = 0.f;

    if (active) {
#pragma unroll 1
        for (int i = 0; i < DIM; ++i) {
            float xv = v[t][i];
            float s  = silu(xv);
            float b[8];
            spline_bases(xv, b);
            const float* wb = Wc + i * DIM;
            const float* ws = Wc + (DIM + i * 8) * DIM;
#pragma unroll
            for (int o = 0; o < DIM; ++o) {
                float a = fmaf(s, wb[o], acc[o]);
                a = fmaf(b[0], ws[o], a);
                a = fmaf(b[1], ws[DIM + o], a);
                a = fmaf(b[2], ws[2 * DIM + o], a);
                a = fmaf(b[3], ws[3 * DIM + o], a);
                a = fmaf(b[4], ws[4 * DIM + o], a);
                a = fmaf(b[5], ws[5 * DIM + o], a);
                a = fmaf(b[6], ws[6 * DIM + o], a);
                a = fmaf(b[7], ws[7 * DIM + o], a);
                acc[o] = a;
            }
        }
        // park results in LDS for a coalesced write-out
#pragma unroll
        for (int o = 0; o < DIM; ++o) v[t][o] = acc[o];
    }
    __syncthreads();

#pragma unroll 4
    for (int j = 0; j < 64; ++j) {
        int idx = base + t + j * 128;
        if (idx < NODES * DIM) {
            int off = t + j * 128;
            out[idx] = v[off >> 6][off & 63];
        }
    }
}

// ---------------------------------------------------------------------------
// pooled[batch[n]] += h[n].  batch is sorted -> run-length local accumulation,
// ~1 atomic per thread instead of 16.
// Block covers 64 nodes: thread = (feature f, node-group of 16 contiguous).
// ---------------------------------------------------------------------------
__global__ void pool_kernel(const float* __restrict__ h, const int* __restrict__ batch,
                            float* __restrict__ pooled) {
    int f  = threadIdx.x & 63;
    int g4 = threadIdx.x >> 6;
    int n0 = blockIdx.x * 64 + g4 * 16;
    float sum = 0.f;
    int cur = -1;
    for (int k = 0; k < 16; ++k) {
        int n = n0 + k;
        if (n >= NODES) break;
        int bb = batch[n];
        if (bb != cur) {
            if (cur >= 0) atomicAdd(&pooled[cur * DIM + f], sum);
            cur = bb;
            sum = 0.f;
        }
        sum += h[n * DIM + f];
    }
    if (cur >= 0) atomicAdd(&pooled[cur * DIM + f], sum);
}

// ---------------------------------------------------------------------------
// out[g][o] = KAN_head(pooled[g]) for 512 graphs, 10 targets.
// ---------------------------------------------------------------------------
__global__ __launch_bounds__(64) void head_kernel(const float* __restrict__ pooled,
                                                  const float* __restrict__ bwh,
                                                  const float* __restrict__ swh,
                                                  const float* __restrict__ sch,
                                                  float* __restrict__ out) {
    __shared__ float v[64][65];
    const int t = threadIdx.x;
    const int base = blockIdx.x * 64 * DIM;
#pragma unroll 4
    for (int j = 0; j < 64; ++j) {
        int off = t + j * 64;
        v[off >> 6][off & 63] = pooled[base + off];
    }
    __syncthreads();

    const int g = blockIdx.x * 64 + t;
    float acc[NT];
#pragma unroll
    for (int o = 0; o < NT; ++o) acc[o] = 0.f;

#pragma unroll 1
    for (int i = 0; i < DIM; ++i) {
        float xv = v[t][i];
        float s  = silu(xv);
        float b[8];
        spline_bases(xv, b);
#pragma unroll
        for (int o = 0; o < NT; ++o) {
            float a = fmaf(s, bwh[o * DIM + i], acc[o]);
            float wsc = sch[o * DIM + i];
            const float* sp = swh + (o * DIM + i) * 8;
            float sb = 0.f;
#pragma unroll
            for (int q = 0; q < 8; ++q) sb = fmaf(b[q], sp[q], sb);
            acc[o] = fmaf(sb, wsc, a);
        }
    }
#pragma unroll
    for (int o = 0; o < NT; ++o) out[g * NT + o] = acc[o];
}

// ---------------------------------------------------------------------------
extern "C" void kernel_launch(void* const* d_in, const int* in_sizes, int n_in,
                              void* d_out, int out_size, void* d_ws, size_t ws_size,
                              hipStream_t stream) {
    const float* x   = (const float*)d_in[0];
    const int*   ei  = (const int*)d_in[1];
    const int*   bat = (const int*)d_in[2];
    const float* bw0 = (const float*)d_in[3];
    const float* sw0 = (const float*)d_in[4];
    const float* sc0 = (const float*)d_in[5];
    const float* bw1 = (const float*)d_in[6];
    const float* sw1 = (const float*)d_in[7];
    const float* sc1 = (const float*)d_in[8];
    const float* bwh = (const float*)d_in[9];
    const float* swh = (const float*)d_in[10];
    const float* sch = (const float*)d_in[11];
    float* out = (float*)d_out;

    float* ws = (float*)d_ws;
    float* Wc0    = ws;                       // 36864
    float* Wc1    = Wc0 + KTOT * DIM;         // 36864
    float* agg    = Wc1 + KTOT * DIM;         // 6.4M
    float* h      = agg + NODES * DIM;        // 6.4M
    float* pooled = h + NODES * DIM;          // 32768

    // fuse spline_w * scaler and transpose base_w once per call
    prep_w<<<(KTOT * DIM + 255) / 256, 256, 0, stream>>>(bw0, sw0, sc0, Wc0);
    prep_w<<<(KTOT * DIM + 255) / 256, 256, 0, stream>>>(bw1, sw1, sc1, Wc1);

    const int scatter_blocks = (EDGES * DIM) / 256;   // 300000
    const int layer_blocks   = (NODES + 127) / 128;   // 782

    // layer 0
    hipMemsetAsync(agg, 0, (size_t)NODES * DIM * sizeof(float), stream);
    scatter_add<<<scatter_blocks, 256, 0, stream>>>(x, ei, agg);
    kan_layer<<<layer_blocks, 128, 0, stream>>>(x, agg, Wc0, h);

    // layer 1 (in place)
    hipMemsetAsync(agg, 0, (size_t)NODES * DIM * sizeof(float), stream);
    scatter_add<<<scatter_blocks, 256, 0, stream>>>(h, ei, agg);
    kan_layer<<<layer_blocks, 128, 0, stream>>>(h, agg, Wc1, h);

    // pool + head
    hipMemsetAsync(pooled, 0, (size_t)GRAPHS * DIM * sizeof(float), stream);
    pool_kernel<<<(NODES + 63) / 64, 256, 0, stream>>>(h, bat, pooled);
    head_kernel<<<GRAPHS / 64, 64, 0, stream>>>(pooled, bwh, swh, sch, out);
}